// Round 1
// baseline (298.182 us; speedup 1.0000x reference)
//
#include <hip/hip_runtime.h>
#include <math.h>

#define D_DIM 512
#define K_DIM 64
#define L_SEQ 1024
#define B_SZ  2
#define M_ROWS (B_SZ*L_SEQ)

__device__ __forceinline__ float gelu_exact(float x) {
    return 0.5f * x * (1.0f + erff(x * 0.70710678118654752f));
}

// ---------------------------------------------------------------------------
// Generic fp32 tiled GEMM: C[M,N] = act(X[M,K] @ W[K,N] + bias) (+ resid)
// BM=BN=64, BK=16, 256 threads, 4x4 microtile per thread.
// M,N multiples of 64; K multiple of 16. Row-major everywhere.
// ---------------------------------------------------------------------------
template<int ACT, bool RESID>
__global__ __launch_bounds__(256) void gemm_kernel(
    const float* __restrict__ X, const float* __restrict__ W,
    const float* __restrict__ bias, const float* __restrict__ resid,
    float* __restrict__ C, int M, int N, int K)
{
    __shared__ float As[16][64];   // As[k][m] (transposed store)
    __shared__ float Bs[16][64];   // Bs[k][n]
    const int tid  = threadIdx.x;
    const int nBase = blockIdx.x * 64;
    const int mBase = blockIdx.y * 64;
    const int tm = tid / 16, tn = tid % 16;
    const int lr  = tid / 4;           // 0..63  (X tile row)
    const int lc4 = (tid % 4) * 4;     // 0,4,8,12 (X tile col group)
    const int wr  = tid / 16;          // 0..15  (W tile row)
    const int wc4 = (tid % 16) * 4;    // 0..60  (W tile col group)

    float acc[4][4] = {};
    for (int kt = 0; kt < K; kt += 16) {
        float4 xa = *reinterpret_cast<const float4*>(X + (size_t)(mBase + lr) * K + kt + lc4);
        float4 wb = *reinterpret_cast<const float4*>(W + (size_t)(kt + wr) * N + nBase + wc4);
        __syncthreads();
        As[lc4+0][lr] = xa.x; As[lc4+1][lr] = xa.y;
        As[lc4+2][lr] = xa.z; As[lc4+3][lr] = xa.w;
        *reinterpret_cast<float4*>(&Bs[wr][wc4]) = wb;
        __syncthreads();
#pragma unroll
        for (int k = 0; k < 16; ++k) {
            float4 a = *reinterpret_cast<const float4*>(&As[k][tm*4]);
            float4 b = *reinterpret_cast<const float4*>(&Bs[k][tn*4]);
            float av[4] = {a.x, a.y, a.z, a.w};
            float bv[4] = {b.x, b.y, b.z, b.w};
#pragma unroll
            for (int i = 0; i < 4; ++i)
#pragma unroll
                for (int j = 0; j < 4; ++j)
                    acc[i][j] += av[i] * bv[j];
        }
    }
#pragma unroll
    for (int i = 0; i < 4; ++i) {
        const int row = mBase + tm*4 + i;
#pragma unroll
        for (int j = 0; j < 4; ++j) {
            const int col = nBase + tn*4 + j;
            float v = acc[i][j] + bias[col];
            if (ACT == 1) v = gelu_exact(v);
            if (RESID)    v += resid[(size_t)row * N + col];
            C[(size_t)row * N + col] = v;
        }
    }
}

// ---------------------------------------------------------------------------
// Phase head: per row, p[j] = tanh(h . W2[:,j] + b2[j]) * pi, write cos|sin
// CS layout: row-major M x 128, cols [0,64) = cos, [64,128) = sin.
// ---------------------------------------------------------------------------
__global__ __launch_bounds__(256) void phase_kernel(
    const float* __restrict__ H, const float* __restrict__ W2,
    const float* __restrict__ b2, float* __restrict__ CS)
{
    const int row = blockIdx.x;
    const int tid = threadIdx.x;
    __shared__ float h[512];
    __shared__ float part[256];
    if (tid < 128)
        reinterpret_cast<float4*>(h)[tid] =
            reinterpret_cast<const float4*>(H + (size_t)row * 512)[tid];
    __syncthreads();
    const int j = tid & 63;
    const int chunk = tid >> 6;   // 0..3, each 128 k's
    float sum = 0.f;
    const int k0 = chunk * 128;
#pragma unroll 8
    for (int k = k0; k < k0 + 128; ++k)
        sum += h[k] * W2[(size_t)k * 64 + j];
    part[tid] = sum;
    __syncthreads();
    if (tid < 64) {
        float p = part[j] + part[j+64] + part[j+128] + part[j+192] + b2[j];
        p = tanhf(p) * 3.14159265358979323846f;
        float s, c;
        sincosf(p, &s, &c);
        CS[(size_t)row * 128 + j]      = c;
        CS[(size_t)row * 128 + 64 + j] = s;
    }
}

// ---------------------------------------------------------------------------
// Scores: A[b,t,s] = sum_k CSq[b,t,k] * CSk[b,s,k]   (K=128), lower-tri tiles
// ---------------------------------------------------------------------------
__global__ __launch_bounds__(256) void scores_kernel(
    const float* __restrict__ CSq, const float* __restrict__ CSk,
    float* __restrict__ A)
{
    const int b  = blockIdx.z;
    const int tT = blockIdx.y, sT = blockIdx.x;
    if (sT > tT) return;
    __shared__ float Qs[16][64];
    __shared__ float Ks[16][64];
    const int tid = threadIdx.x;
    const int lr = tid / 4, lc4 = (tid % 4) * 4;
    const int tm = tid / 16, tn = tid % 16;
    const float* Qb = CSq + ((size_t)(b * L_SEQ + tT * 64)) * 128;
    const float* Kb = CSk + ((size_t)(b * L_SEQ + sT * 64)) * 128;
    float acc[4][4] = {};
    for (int kt = 0; kt < 128; kt += 16) {
        float4 q = *reinterpret_cast<const float4*>(Qb + (size_t)lr * 128 + kt + lc4);
        float4 k = *reinterpret_cast<const float4*>(Kb + (size_t)lr * 128 + kt + lc4);
        __syncthreads();
        Qs[lc4+0][lr] = q.x; Qs[lc4+1][lr] = q.y;
        Qs[lc4+2][lr] = q.z; Qs[lc4+3][lr] = q.w;
        Ks[lc4+0][lr] = k.x; Ks[lc4+1][lr] = k.y;
        Ks[lc4+2][lr] = k.z; Ks[lc4+3][lr] = k.w;
        __syncthreads();
#pragma unroll
        for (int kk = 0; kk < 16; ++kk) {
            float4 a = *reinterpret_cast<const float4*>(&Qs[kk][tm*4]);
            float4 bq = *reinterpret_cast<const float4*>(&Ks[kk][tn*4]);
            float av[4] = {a.x, a.y, a.z, a.w};
            float bv[4] = {bq.x, bq.y, bq.z, bq.w};
#pragma unroll
            for (int i = 0; i < 4; ++i)
#pragma unroll
                for (int j = 0; j < 4; ++j)
                    acc[i][j] += av[i] * bv[j];
        }
    }
    float* Ab = A + ((size_t)b * L_SEQ + tT * 64) * L_SEQ + sT * 64;
#pragma unroll
    for (int i = 0; i < 4; ++i)
#pragma unroll
        for (int j = 0; j < 4; ++j)
            Ab[(size_t)(tm*4 + i) * L_SEQ + tn*4 + j] = acc[i][j];
}

// ---------------------------------------------------------------------------
// Causal AV: R[b,t,d] = sum_{s<=t} A[b,t,s] * V[b,s,d]
// ---------------------------------------------------------------------------
__global__ __launch_bounds__(256) void av_kernel(
    const float* __restrict__ A, const float* __restrict__ V,
    float* __restrict__ R)
{
    const int b = blockIdx.z, tT = blockIdx.y, dT = blockIdx.x;
    __shared__ float As_[16][64];
    __shared__ float Vs[16][64];
    const int tid = threadIdx.x;
    const int lr = tid / 4, lc4 = (tid % 4) * 4;
    const int wr = tid / 16, wc4 = (tid % 16) * 4;
    const int tm = tid / 16, tn = tid % 16;
    const int tBase = tT * 64;
    const int kEnd = tBase + 64;
    float acc[4][4] = {};
    for (int kt = 0; kt < kEnd; kt += 16) {
        float4 a4 = *reinterpret_cast<const float4*>(
            A + ((size_t)b * L_SEQ + tBase + lr) * L_SEQ + kt + lc4);
        float4 v4 = *reinterpret_cast<const float4*>(
            V + ((size_t)(b * L_SEQ + kt + wr)) * D_DIM + dT * 64 + wc4);
        if (kt >= tBase) {   // diagonal tile: mask s > t
            const int tg = tBase + lr;
            if (kt + lc4 + 0 > tg) a4.x = 0.f;
            if (kt + lc4 + 1 > tg) a4.y = 0.f;
            if (kt + lc4 + 2 > tg) a4.z = 0.f;
            if (kt + lc4 + 3 > tg) a4.w = 0.f;
        }
        __syncthreads();
        As_[lc4+0][lr] = a4.x; As_[lc4+1][lr] = a4.y;
        As_[lc4+2][lr] = a4.z; As_[lc4+3][lr] = a4.w;
        *reinterpret_cast<float4*>(&Vs[wr][wc4]) = v4;
        __syncthreads();
#pragma unroll
        for (int kk = 0; kk < 16; ++kk) {
            float4 a = *reinterpret_cast<const float4*>(&As_[kk][tm*4]);
            float4 v = *reinterpret_cast<const float4*>(&Vs[kk][tn*4]);
            float av[4] = {a.x, a.y, a.z, a.w};
            float vv[4] = {v.x, v.y, v.z, v.w};
#pragma unroll
            for (int i = 0; i < 4; ++i)
#pragma unroll
                for (int j = 0; j < 4; ++j)
                    acc[i][j] += av[i] * vv[j];
        }
    }
    float* Rb = R + ((size_t)(b * L_SEQ + tBase)) * D_DIM + dT * 64;
#pragma unroll
    for (int i = 0; i < 4; ++i)
#pragma unroll
        for (int j = 0; j < 4; ++j)
            Rb[(size_t)(tm*4 + i) * D_DIM + tn*4 + j] = acc[i][j];
}

// ---------------------------------------------------------------------------
// LayerNorm of R/norm(t); Y = LN * g + b. norm = sqrt((t+1)*K)
// ---------------------------------------------------------------------------
__global__ __launch_bounds__(256) void ln_kernel(
    const float* __restrict__ R, const float* __restrict__ g,
    const float* __restrict__ bb, float* __restrict__ Y)
{
    const int row = blockIdx.x;
    const int t = row & (L_SEQ - 1);
    const int tid = threadIdx.x;
    const float scale = rsqrtf((float)(t + 1) * (float)K_DIM);
    const float v0 = R[(size_t)row * 512 + tid] * scale;
    const float v1 = R[(size_t)row * 512 + 256 + tid] * scale;
    __shared__ float sbuf[512];
    sbuf[tid]       = v0 + v1;
    sbuf[256 + tid] = v0 * v0 + v1 * v1;
    __syncthreads();
    for (int off = 128; off > 0; off >>= 1) {
        if (tid < off) {
            sbuf[tid]       += sbuf[tid + off];
            sbuf[256 + tid] += sbuf[256 + tid + off];
        }
        __syncthreads();
    }
    const float mu  = sbuf[0] * (1.f / 512.f);
    const float var = sbuf[256] * (1.f / 512.f) - mu * mu;
    const float r = rsqrtf(var + 1e-5f);
    Y[(size_t)row * 512 + tid]       = (v0 - mu) * r * g[tid]       + bb[tid];
    Y[(size_t)row * 512 + 256 + tid] = (v1 - mu) * r * g[256 + tid] + bb[256 + tid];
}

// ---------------------------------------------------------------------------
extern "C" void kernel_launch(void* const* d_in, const int* in_sizes, int n_in,
                              void* d_out, int out_size, void* d_ws, size_t ws_size,
                              hipStream_t stream)
{
    const float* x   = (const float*)d_in[0];
    const float* Wk1 = (const float*)d_in[1];
    const float* bk1 = (const float*)d_in[2];
    const float* Wk2 = (const float*)d_in[3];
    const float* bk2 = (const float*)d_in[4];
    const float* Wq1 = (const float*)d_in[5];
    const float* bq1 = (const float*)d_in[6];
    const float* Wq2 = (const float*)d_in[7];
    const float* bq2 = (const float*)d_in[8];
    const float* Wv  = (const float*)d_in[9];
    const float* bv  = (const float*)d_in[10];
    const float* lng = (const float*)d_in[11];
    const float* lnb = (const float*)d_in[12];
    const float* Wo  = (const float*)d_in[13];
    const float* bo  = (const float*)d_in[14];
    float* out = (float*)d_out;

    float* ws = (float*)d_ws;
    float* H   = ws;                       // 2048*512
    float* CSk = H   + (size_t)M_ROWS * 512;   // 2048*128
    float* CSq = CSk + (size_t)M_ROWS * 128;
    float* V   = CSq + (size_t)M_ROWS * 128;   // 2048*512
    float* Amat= V   + (size_t)M_ROWS * 512;   // 2*1024*1024
    float* R   = Amat+ (size_t)B_SZ * L_SEQ * L_SEQ; // 2048*512
    float* Y   = R   + (size_t)M_ROWS * 512;

    const dim3 gBig(D_DIM / 64, M_ROWS / 64);  // (8, 32)
    // key encoder layer1 + phase
    gemm_kernel<1, false><<<gBig, 256, 0, stream>>>(x, Wk1, bk1, nullptr, H, M_ROWS, D_DIM, D_DIM);
    phase_kernel<<<M_ROWS, 256, 0, stream>>>(H, Wk2, bk2, CSk);
    // query encoder layer1 + phase
    gemm_kernel<1, false><<<gBig, 256, 0, stream>>>(x, Wq1, bq1, nullptr, H, M_ROWS, D_DIM, D_DIM);
    phase_kernel<<<M_ROWS, 256, 0, stream>>>(H, Wq2, bq2, CSq);
    // value
    gemm_kernel<0, false><<<gBig, 256, 0, stream>>>(x, Wv, bv, nullptr, V, M_ROWS, D_DIM, D_DIM);
    // scores (lower-triangular tiles)
    scores_kernel<<<dim3(L_SEQ/64, L_SEQ/64, B_SZ), 256, 0, stream>>>(CSq, CSk, Amat);
    // causal AV
    av_kernel<<<dim3(D_DIM/64, L_SEQ/64, B_SZ), 256, 0, stream>>>(Amat, V, R);
    // LN(R / norm)
    ln_kernel<<<M_ROWS, 256, 0, stream>>>(R, lng, lnb, Y);
    // out = x + Y @ Wo + bo
    gemm_kernel<0, true><<<gBig, 256, 0, stream>>>(Y, Wo, bo, x, out, M_ROWS, D_DIM, D_DIM);
}

// Round 2
// 236.508 us; speedup vs baseline: 1.2608x; 1.2608x over previous
//
#include <hip/hip_runtime.h>
#include <math.h>

#define D_DIM 512
#define K_DIM 64
#define L_SEQ 1024
#define B_SZ  2
#define M_ROWS (B_SZ*L_SEQ)

__device__ __forceinline__ float gelu_exact(float x) {
    return 0.5f * x * (1.0f + erff(x * 0.70710678118654752f));
}

// ---------------------------------------------------------------------------
// Fused QKV GEMM: HKQV[M,1536] = act( X[M,512] @ [Wk1 | Wq1 | Wv] + bias )
// GELU on first two 512-col segments, none on V segment.
// 64x64 tiles, BK=16, 256 threads, 4x4 microtile. LDS padded stride 68.
// ---------------------------------------------------------------------------
__global__ __launch_bounds__(256, 4) void qkv_kernel(
    const float* __restrict__ X,
    const float* __restrict__ Wk1, const float* __restrict__ bk1,
    const float* __restrict__ Wq1, const float* __restrict__ bq1,
    const float* __restrict__ Wv,  const float* __restrict__ bv,
    float* __restrict__ HKQV)
{
    __shared__ float As[16][68];
    __shared__ float Bs[16][68];
    const int tid = threadIdx.x;
    const int nG   = blockIdx.x * 64;      // 0..1535
    const int mBase = blockIdx.y * 64;
    const int seg  = nG >> 9;              // 0=k,1=q,2=v
    const int nW   = nG & 511;             // col within segment
    const float* W    = (seg == 0) ? Wk1 : (seg == 1) ? Wq1 : Wv;
    const float* bias = (seg == 0) ? bk1 : (seg == 1) ? bq1 : bv;

    const int tm = tid / 16, tn = tid % 16;
    const int lr  = tid / 4,  lc4 = (tid % 4) * 4;
    const int wr  = tid / 16, wc4 = (tid % 16) * 4;

    float acc[4][4] = {};
    for (int kt = 0; kt < 512; kt += 16) {
        float4 xa = *reinterpret_cast<const float4*>(X + (size_t)(mBase + lr) * 512 + kt + lc4);
        float4 wb = *reinterpret_cast<const float4*>(W + (size_t)(kt + wr) * 512 + nW + wc4);
        __syncthreads();
        As[lc4+0][lr] = xa.x; As[lc4+1][lr] = xa.y;
        As[lc4+2][lr] = xa.z; As[lc4+3][lr] = xa.w;
        *reinterpret_cast<float4*>(&Bs[wr][wc4]) = wb;
        __syncthreads();
#pragma unroll
        for (int k = 0; k < 16; ++k) {
            float4 a = *reinterpret_cast<const float4*>(&As[k][tm*4]);
            float4 b = *reinterpret_cast<const float4*>(&Bs[k][tn*4]);
            float av[4] = {a.x, a.y, a.z, a.w};
            float bv2[4] = {b.x, b.y, b.z, b.w};
#pragma unroll
            for (int i = 0; i < 4; ++i)
#pragma unroll
                for (int j = 0; j < 4; ++j)
                    acc[i][j] += av[i] * bv2[j];
        }
    }
#pragma unroll
    for (int i = 0; i < 4; ++i) {
        const int row = mBase + tm*4 + i;
#pragma unroll
        for (int j = 0; j < 4; ++j) {
            const int colW = nW + tn*4 + j;
            float v = acc[i][j] + bias[colW];
            if (seg < 2) v = gelu_exact(v);
            HKQV[(size_t)row * 1536 + nG + tn*4 + j] = v;
        }
    }
}

// ---------------------------------------------------------------------------
// Phase head (k and q in one launch; blockIdx.y selects).
// p[j] = tanh(h . W2[:,j] + b2[j]) * pi -> CS row: [cos(64) | sin(64)]
// ---------------------------------------------------------------------------
__global__ __launch_bounds__(256, 4) void phase_kernel(
    const float* __restrict__ HKQV,
    const float* __restrict__ Wk2, const float* __restrict__ bk2,
    const float* __restrict__ Wq2, const float* __restrict__ bq2,
    float* __restrict__ CSk, float* __restrict__ CSq)
{
    const int row = blockIdx.x;
    const int which = blockIdx.y;     // 0 = key, 1 = query
    const float* W2 = which ? Wq2 : Wk2;
    const float* b2 = which ? bq2 : bk2;
    float* CS = which ? CSq : CSk;
    const int tid = threadIdx.x;
    __shared__ float h[512];
    __shared__ float part[256];
    const float* Hrow = HKQV + (size_t)row * 1536 + (which ? 512 : 0);
    if (tid < 128)
        reinterpret_cast<float4*>(h)[tid] = reinterpret_cast<const float4*>(Hrow)[tid];
    __syncthreads();
    const int j = tid & 63;
    const int k0 = (tid >> 6) * 128;
    float sum = 0.f;
#pragma unroll 8
    for (int k = k0; k < k0 + 128; ++k)
        sum += h[k] * W2[(size_t)k * 64 + j];
    part[tid] = sum;
    __syncthreads();
    if (tid < 64) {
        float p = part[j] + part[j+64] + part[j+128] + part[j+192] + b2[j];
        p = tanhf(p) * 3.14159265358979323846f;
        float s, c;
        sincosf(p, &s, &c);
        CS[(size_t)row * 128 + j]      = c;
        CS[(size_t)row * 128 + 64 + j] = s;
    }
}

// ---------------------------------------------------------------------------
// Scores: A[b,t,s] = CSq[b,t,:] . CSk[b,s,:]  (K=128), 32x32 tiles, lower-tri
// Whole K staged in LDS once (no K loop barriers).
// ---------------------------------------------------------------------------
__global__ __launch_bounds__(256, 4) void scores_kernel(
    const float* __restrict__ CSq, const float* __restrict__ CSk,
    float* __restrict__ A)
{
    const int sT = blockIdx.x, tT = blockIdx.y, b = blockIdx.z;
    if (sT > tT) return;
    __shared__ float Qs[128][36];
    __shared__ float Ks[128][36];
    const int tid = threadIdx.x;
    const int tBase = tT * 32, sBase = sT * 32;
    const float* Qg = CSq + ((size_t)(b * L_SEQ + tBase)) * 128;
    const float* Kg = CSk + ((size_t)(b * L_SEQ + sBase)) * 128;
    const int qr = tid >> 3;            // 0..31
    const int k0 = (tid & 7) * 16;      // 0..112
#pragma unroll
    for (int i = 0; i < 4; ++i) {
        float4 v = *reinterpret_cast<const float4*>(Qg + (size_t)qr * 128 + k0 + 4*i);
        Qs[k0+4*i+0][qr] = v.x; Qs[k0+4*i+1][qr] = v.y;
        Qs[k0+4*i+2][qr] = v.z; Qs[k0+4*i+3][qr] = v.w;
        float4 w = *reinterpret_cast<const float4*>(Kg + (size_t)qr * 128 + k0 + 4*i);
        Ks[k0+4*i+0][qr] = w.x; Ks[k0+4*i+1][qr] = w.y;
        Ks[k0+4*i+2][qr] = w.z; Ks[k0+4*i+3][qr] = w.w;
    }
    __syncthreads();
    const int tm = tid >> 4, tn = tid & 15;
    float acc[2][2] = {};
#pragma unroll 4
    for (int k = 0; k < 128; ++k) {
        float2 q = *reinterpret_cast<const float2*>(&Qs[k][tm*2]);
        float2 s = *reinterpret_cast<const float2*>(&Ks[k][tn*2]);
        acc[0][0] += q.x * s.x; acc[0][1] += q.x * s.y;
        acc[1][0] += q.y * s.x; acc[1][1] += q.y * s.y;
    }
    float* Ab = A + ((size_t)b << 20);
#pragma unroll
    for (int i = 0; i < 2; ++i)
#pragma unroll
        for (int j = 0; j < 2; ++j)
            Ab[(size_t)(tBase + tm*2 + i) * L_SEQ + sBase + tn*2 + j] = acc[i][j];
}

// ---------------------------------------------------------------------------
// Causal AV, s-split into 4 chunks of 256 -> partials Rp[c].
// Rp[c][b,t,d] = sum_{s in chunk c, s<=t} A[b,t,s] * V[b,s,d]
// ---------------------------------------------------------------------------
__global__ __launch_bounds__(256, 4) void av_kernel(
    const float* __restrict__ A, const float* __restrict__ HKQV,
    float* __restrict__ Rp)
{
    const int dT = blockIdx.x, tT = blockIdx.y;
    const int b = blockIdx.z >> 2, c = blockIdx.z & 3;
    if (c > (tT >> 2)) return;
    __shared__ float As_[16][68];
    __shared__ float Vs[16][68];
    const int tid = threadIdx.x;
    const int lr = tid / 4, lc4 = (tid % 4) * 4;
    const int wr = tid / 16, wc4 = (tid % 16) * 4;
    const int tm = tid / 16, tn = tid % 16;
    const int tBase = tT * 64;
    const int s0 = c * 256;
    const int sEnd = min(s0 + 256, tBase + 64);
    float acc[4][4] = {};
    for (int kt = s0; kt < sEnd; kt += 16) {
        float4 a4 = *reinterpret_cast<const float4*>(
            A + ((size_t)b << 20) + (size_t)(tBase + lr) * L_SEQ + kt + lc4);
        // V lives in HKQV cols [1024,1536)
        float4 v4 = *reinterpret_cast<const float4*>(
            HKQV + (size_t)(b * L_SEQ + kt + wr) * 1536 + 1024 + dT * 64 + wc4);
        if (kt >= tBase) {   // diagonal 64-block: mask s > t
            const int tg = tBase + lr;
            if (kt + lc4 + 0 > tg) a4.x = 0.f;
            if (kt + lc4 + 1 > tg) a4.y = 0.f;
            if (kt + lc4 + 2 > tg) a4.z = 0.f;
            if (kt + lc4 + 3 > tg) a4.w = 0.f;
        }
        __syncthreads();
        As_[lc4+0][lr] = a4.x; As_[lc4+1][lr] = a4.y;
        As_[lc4+2][lr] = a4.z; As_[lc4+3][lr] = a4.w;
        *reinterpret_cast<float4*>(&Vs[wr][wc4]) = v4;
        __syncthreads();
#pragma unroll
        for (int kk = 0; kk < 16; ++kk) {
            float4 a = *reinterpret_cast<const float4*>(&As_[kk][tm*4]);
            float4 v = *reinterpret_cast<const float4*>(&Vs[kk][tn*4]);
            float av[4] = {a.x, a.y, a.z, a.w};
            float vv[4] = {v.x, v.y, v.z, v.w};
#pragma unroll
            for (int i = 0; i < 4; ++i)
#pragma unroll
                for (int j = 0; j < 4; ++j)
                    acc[i][j] += av[i] * vv[j];
        }
    }
    float* Rb = Rp + (size_t)c * M_ROWS * 512
                  + (size_t)(b * L_SEQ + tBase) * 512 + dT * 64;
#pragma unroll
    for (int i = 0; i < 4; ++i)
#pragma unroll
        for (int j = 0; j < 4; ++j)
            Rb[(size_t)(tm*4 + i) * 512 + tn*4 + j] = acc[i][j];
}

// ---------------------------------------------------------------------------
// LN( (sum_c Rp[c]) / sqrt((t+1)*K) ) * g + b -> Y   (Y aliases Rp[0]: safe,
// each block reads its own row's partials before writing that row)
// ---------------------------------------------------------------------------
__global__ __launch_bounds__(256, 4) void ln_kernel(
    const float* __restrict__ Rp, const float* __restrict__ g,
    const float* __restrict__ bb, float* __restrict__ Y)
{
    const int row = blockIdx.x;
    const int t = row & (L_SEQ - 1);
    const int nc = (t >> 8) + 1;           // chunks contributing to this row
    const int tid = threadIdx.x;
    const float scale = rsqrtf((float)(t + 1) * (float)K_DIM);
    float v0 = 0.f, v1 = 0.f;
    for (int c = 0; c < nc; ++c) {
        const float* Rr = Rp + (size_t)c * M_ROWS * 512 + (size_t)row * 512;
        v0 += Rr[tid];
        v1 += Rr[256 + tid];
    }
    v0 *= scale; v1 *= scale;
    __shared__ float sbuf[512];
    sbuf[tid]       = v0 + v1;
    sbuf[256 + tid] = v0 * v0 + v1 * v1;
    __syncthreads();
    for (int off = 128; off > 0; off >>= 1) {
        if (tid < off) {
            sbuf[tid]       += sbuf[tid + off];
            sbuf[256 + tid] += sbuf[256 + tid + off];
        }
        __syncthreads();
    }
    const float mu  = sbuf[0] * (1.f / 512.f);
    const float var = sbuf[256] * (1.f / 512.f) - mu * mu;
    const float r = rsqrtf(var + 1e-5f);
    Y[(size_t)row * 512 + tid]       = (v0 - mu) * r * g[tid]       + bb[tid];
    Y[(size_t)row * 512 + 256 + tid] = (v1 - mu) * r * g[256 + tid] + bb[256 + tid];
}

// ---------------------------------------------------------------------------
// Output projection: out = x + Y @ Wo + bo. 32x64 tiles -> 512 blocks.
// ---------------------------------------------------------------------------
__global__ __launch_bounds__(256, 4) void out_kernel(
    const float* __restrict__ Y, const float* __restrict__ Wo,
    const float* __restrict__ bo, const float* __restrict__ x,
    float* __restrict__ out)
{
    __shared__ float As[16][36];
    __shared__ float Bs[16][68];
    const int tid = threadIdx.x;
    const int nBase = blockIdx.x * 64;
    const int mBase = blockIdx.y * 32;
    const int tm = tid >> 4, tn = tid & 15;     // 16x16 threads, 2x4 micro
    const int wr = tid >> 4, wc4 = (tid & 15) * 4;
    float acc[2][4] = {};
    for (int kt = 0; kt < 512; kt += 16) {
        float4 xa;
        if (tid < 128) {
            const int xr = tid >> 2, xc4 = (tid & 3) * 4;
            xa = *reinterpret_cast<const float4*>(Y + (size_t)(mBase + xr) * 512 + kt + xc4);
        }
        float4 wb = *reinterpret_cast<const float4*>(Wo + (size_t)(kt + wr) * 512 + nBase + wc4);
        __syncthreads();
        if (tid < 128) {
            const int xr = tid >> 2, xc4 = (tid & 3) * 4;
            As[xc4+0][xr] = xa.x; As[xc4+1][xr] = xa.y;
            As[xc4+2][xr] = xa.z; As[xc4+3][xr] = xa.w;
        }
        *reinterpret_cast<float4*>(&Bs[wr][wc4]) = wb;
        __syncthreads();
#pragma unroll
        for (int k = 0; k < 16; ++k) {
            float2 a = *reinterpret_cast<const float2*>(&As[k][tm*2]);
            float4 b = *reinterpret_cast<const float4*>(&Bs[k][tn*4]);
            float av[2] = {a.x, a.y};
            float bv[4] = {b.x, b.y, b.z, b.w};
#pragma unroll
            for (int i = 0; i < 2; ++i)
#pragma unroll
                for (int j = 0; j < 4; ++j)
                    acc[i][j] += av[i] * bv[j];
        }
    }
#pragma unroll
    for (int i = 0; i < 2; ++i) {
        const int row = mBase + tm*2 + i;
#pragma unroll
        for (int j = 0; j < 4; ++j) {
            const int col = nBase + tn*4 + j;
            out[(size_t)row * 512 + col] =
                acc[i][j] + bo[col] + x[(size_t)row * 512 + col];
        }
    }
}

// ---------------------------------------------------------------------------
extern "C" void kernel_launch(void* const* d_in, const int* in_sizes, int n_in,
                              void* d_out, int out_size, void* d_ws, size_t ws_size,
                              hipStream_t stream)
{
    const float* x   = (const float*)d_in[0];
    const float* Wk1 = (const float*)d_in[1];
    const float* bk1 = (const float*)d_in[2];
    const float* Wk2 = (const float*)d_in[3];
    const float* bk2 = (const float*)d_in[4];
    const float* Wq1 = (const float*)d_in[5];
    const float* bq1 = (const float*)d_in[6];
    const float* Wq2 = (const float*)d_in[7];
    const float* bq2 = (const float*)d_in[8];
    const float* Wv  = (const float*)d_in[9];
    const float* bv  = (const float*)d_in[10];
    const float* lng = (const float*)d_in[11];
    const float* lnb = (const float*)d_in[12];
    const float* Wo  = (const float*)d_in[13];
    const float* bo  = (const float*)d_in[14];
    float* out = (float*)d_out;

    float* ws = (float*)d_ws;
    float* HKQV = ws;                                    // 2048*1536
    float* CSk  = HKQV + (size_t)M_ROWS * 1536;          // 2048*128
    float* CSq  = CSk  + (size_t)M_ROWS * 128;           // 2048*128
    float* Amat = CSq  + (size_t)M_ROWS * 128;           // 2*1024*1024
    float* Rp   = Amat + (size_t)B_SZ * L_SEQ * L_SEQ;   // 4 * 2048*512
    float* Y    = Rp;                                    // alias Rp[0] (safe)

    qkv_kernel<<<dim3(24, 32), 256, 0, stream>>>(
        x, Wk1, bk1, Wq1, bq1, Wv, bv, HKQV);
    phase_kernel<<<dim3(M_ROWS, 2), 256, 0, stream>>>(
        HKQV, Wk2, bk2, Wq2, bq2, CSk, CSq);
    scores_kernel<<<dim3(32, 32, B_SZ), 256, 0, stream>>>(CSq, CSk, Amat);
    av_kernel<<<dim3(8, 16, B_SZ * 4), 256, 0, stream>>>(Amat, HKQV, Rp);
    ln_kernel<<<M_ROWS, 256, 0, stream>>>(Rp, lng, lnb, Y);
    out_kernel<<<dim3(8, 64), 256, 0, stream>>>(Y, Wo, bo, x, out);
}

// Round 4
// 226.749 us; speedup vs baseline: 1.3150x; 1.0430x over previous
//
#include <hip/hip_runtime.h>
#include <math.h>

#define L_SEQ 1024
#define M_ROWS 2048
#define PI_F 3.14159265358979323846f

typedef short bf16x8 __attribute__((ext_vector_type(8)));
typedef float f32x4 __attribute__((ext_vector_type(4)));
typedef unsigned short ushort4v __attribute__((ext_vector_type(4)));

__device__ __forceinline__ unsigned short bf16_rne(float x) {
    union { float f; unsigned u; } v; v.f = x;
    unsigned r = v.u + 0x7fffu + ((v.u >> 16) & 1u);
    return (unsigned short)(r >> 16);
}
__device__ __forceinline__ float bf16_tof(unsigned short h) {
    union { unsigned u; float f; } v; v.u = ((unsigned)h) << 16;
    return v.f;
}
__device__ __forceinline__ void split2(float x, unsigned short &h, unsigned short &l) {
    h = bf16_rne(x);
    l = bf16_rne(x - bf16_tof(h));
}
__device__ __forceinline__ float gelu_exact(float x) {
    return 0.5f * x * (1.0f + erff(x * 0.70710678118654752f));
}
__device__ __forceinline__ f32x4 mfma16(bf16x8 a, bf16x8 b, f32x4 c) {
    return __builtin_amdgcn_mfma_f32_16x16x32_bf16(a, b, c, 0, 0, 0);
}

// ---------------------------------------------------------------------------
// Wave-level 32x32 split-bf16 GEMM core, fragments direct from global (L2).
// C[32x32] = sum_k A[aRow..aRow+31][k] * B[bRow..bRow+31][k]  (B holds the
// k-contiguous transposed operand). acc[mi][ni] per mfma_f32_16x16x32_bf16:
// C row = mi*16 + (lane>>4)*4 + r, col = ni*16 + (lane&15).
// ---------------------------------------------------------------------------
__device__ __forceinline__ void wave_gemm32(
    const unsigned short* __restrict__ Ah, const unsigned short* __restrict__ Al,
    int lda, int aRow,
    const unsigned short* __restrict__ Bh, const unsigned short* __restrict__ Bl,
    int ldb, int bRow,
    int nk, f32x4 (&acc)[2][2])
{
    const int lane = threadIdx.x & 63;
    const int lr = lane & 15;
    const int lk = (lane >> 4) << 3;
    const size_t a0 = (size_t)(aRow + lr) * lda + lk;
    const size_t a1 = a0 + (size_t)16 * lda;
    const size_t b0 = (size_t)(bRow + lr) * ldb + lk;
    const size_t b1 = b0 + (size_t)16 * ldb;
#define LDF(P, O, K) (*reinterpret_cast<const bf16x8*>((P) + (O) + (size_t)(K)))
    bf16x8 a0h = LDF(Ah,a0,0), a0l = LDF(Al,a0,0);
    bf16x8 a1h = LDF(Ah,a1,0), a1l = LDF(Al,a1,0);
    bf16x8 b0h = LDF(Bh,b0,0), b0l = LDF(Bl,b0,0);
    bf16x8 b1h = LDF(Bh,b1,0), b1l = LDF(Bl,b1,0);
#pragma unroll 2
    for (int ks = 0; ks < nk; ++ks) {
        const int kn = (ks + 1 < nk ? ks + 1 : ks) * 32;
        bf16x8 na0h = LDF(Ah,a0,kn), na0l = LDF(Al,a0,kn);
        bf16x8 na1h = LDF(Ah,a1,kn), na1l = LDF(Al,a1,kn);
        bf16x8 nb0h = LDF(Bh,b0,kn), nb0l = LDF(Bl,b0,kn);
        bf16x8 nb1h = LDF(Bh,b1,kn), nb1l = LDF(Bl,b1,kn);
        acc[0][0] = mfma16(a0h, b0h, acc[0][0]);
        acc[0][0] = mfma16(a0h, b0l, acc[0][0]);
        acc[0][0] = mfma16(a0l, b0h, acc[0][0]);
        acc[0][1] = mfma16(a0h, b1h, acc[0][1]);
        acc[0][1] = mfma16(a0h, b1l, acc[0][1]);
        acc[0][1] = mfma16(a0l, b1h, acc[0][1]);
        acc[1][0] = mfma16(a1h, b0h, acc[1][0]);
        acc[1][0] = mfma16(a1h, b0l, acc[1][0]);
        acc[1][0] = mfma16(a1l, b0h, acc[1][0]);
        acc[1][1] = mfma16(a1h, b1h, acc[1][1]);
        acc[1][1] = mfma16(a1h, b1l, acc[1][1]);
        acc[1][1] = mfma16(a1l, b1h, acc[1][1]);
        a0h=na0h; a0l=na0l; a1h=na1h; a1l=na1l;
        b0h=nb0h; b0l=nb0l; b1h=nb1h; b1l=nb1l;
    }
#undef LDF
}

__device__ __forceinline__ void acc_zero(f32x4 (&acc)[2][2]) {
#pragma unroll
    for (int i = 0; i < 2; ++i)
#pragma unroll
        for (int j = 0; j < 2; ++j)
            acc[i][j] = (f32x4){0.f, 0.f, 0.f, 0.f};
}

// ---------------------------------------------------------------------------
// prep_w: transpose + hi/lo split all weights into Wt[row=n][k] bf16.
// dst rows: [0,512)=Wk1^T, [512,1024)=Wq1^T, [1024,1536)=Wv^T,
//           [1536,2048)=Wo^T, [2048,2112)=Wk2^T, [2112,2176)=Wq2^T
// ---------------------------------------------------------------------------
__global__ __launch_bounds__(256) void prep_w(
    const float* __restrict__ Wk1, const float* __restrict__ Wq1,
    const float* __restrict__ Wv,  const float* __restrict__ Wo,
    const float* __restrict__ Wk2, const float* __restrict__ Wq2,
    unsigned short* __restrict__ Wt_h, unsigned short* __restrict__ Wt_l)
{
    const int ty = blockIdx.y;   // 0..33
    const int kT = blockIdx.x;   // 0..7
    const float* src; int srcN; int dstRowBase; int nBase;
    if (ty < 8)       { src = Wk1; srcN = 512; dstRowBase = 0;    nBase = ty * 64; }
    else if (ty < 16) { src = Wq1; srcN = 512; dstRowBase = 512;  nBase = (ty-8)*64; }
    else if (ty < 24) { src = Wv;  srcN = 512; dstRowBase = 1024; nBase = (ty-16)*64; }
    else if (ty < 32) { src = Wo;  srcN = 512; dstRowBase = 1536; nBase = (ty-24)*64; }
    else if (ty == 32){ src = Wk2; srcN = 64;  dstRowBase = 2048; nBase = 0; }
    else              { src = Wq2; srcN = 64;  dstRowBase = 2112; nBase = 0; }
    __shared__ float T[64][65];
    const int tid = threadIdx.x;
    const int k0 = kT * 64;
    {
        const int r = tid >> 2;
        const int c0 = (tid & 3) * 16;
#pragma unroll
        for (int i = 0; i < 4; ++i) {
            float4 v = *reinterpret_cast<const float4*>(
                src + (size_t)(k0 + r) * srcN + nBase + c0 + i*4);
            T[r][c0+i*4+0] = v.x; T[r][c0+i*4+1] = v.y;
            T[r][c0+i*4+2] = v.z; T[r][c0+i*4+3] = v.w;
        }
    }
    __syncthreads();
    {
        const int n = tid >> 2;
        const int kk0 = (tid & 3) * 16;
        const size_t base = (size_t)(dstRowBase + nBase + n) * 512 + k0 + kk0;
#pragma unroll
        for (int i = 0; i < 16; ++i) {
            unsigned short h, l;
            split2(T[kk0 + i][n], h, l);
            Wt_h[base + i] = h; Wt_l[base + i] = l;
        }
    }
}

// x [2048][512] f32 -> Xh, Xl bf16 (no transpose)
__global__ __launch_bounds__(256) void prep_x(
    const float* __restrict__ x,
    unsigned short* __restrict__ Xh, unsigned short* __restrict__ Xl)
{
    const size_t i = (size_t)blockIdx.x * 256 + threadIdx.x;  // float4 index
    float4 v = reinterpret_cast<const float4*>(x)[i];
    ushort4v h, l;
    unsigned short th, tl;
    split2(v.x, th, tl); h[0] = th; l[0] = tl;
    split2(v.y, th, tl); h[1] = th; l[1] = tl;
    split2(v.z, th, tl); h[2] = th; l[2] = tl;
    split2(v.w, th, tl); h[3] = th; l[3] = tl;
    reinterpret_cast<ushort4v*>(Xh)[i] = h;
    reinterpret_cast<ushort4v*>(Xl)[i] = l;
}

// ---------------------------------------------------------------------------
// Fused QKV: cols [0,512)=gelu(x@Wk1+bk1)->Hk, [512,1024)=gelu(x@Wq1+bq1)->Hq,
// [1024,1536)=x@Wv+bv -> Vt (transposed per batch: Vt[b*512+d][s]).
// ---------------------------------------------------------------------------
__global__ __launch_bounds__(256) void qkv_mfma(
    const unsigned short* __restrict__ Xh, const unsigned short* __restrict__ Xl,
    const unsigned short* __restrict__ Wt_h, const unsigned short* __restrict__ Wt_l,
    const float* __restrict__ bk1, const float* __restrict__ bq1, const float* __restrict__ bv,
    unsigned short* __restrict__ Hk_h, unsigned short* __restrict__ Hk_l,
    unsigned short* __restrict__ Hq_h, unsigned short* __restrict__ Hq_l,
    unsigned short* __restrict__ Vt_h, unsigned short* __restrict__ Vt_l)
{
    const int wid = threadIdx.x >> 6, lane = threadIdx.x & 63;
    const int tTile = blockIdx.y * 4 + wid;
    const int colBase = blockIdx.x * 32;
    const int rowBase = tTile * 32;
    f32x4 acc[2][2]; acc_zero(acc);
    wave_gemm32(Xh, Xl, 512, rowBase, Wt_h, Wt_l, 512, colBase, 16, acc);
    const int seg = colBase >> 9;
    const float* bias = (seg == 0) ? bk1 : (seg == 1) ? bq1 : bv;
#pragma unroll
    for (int mi = 0; mi < 2; ++mi)
#pragma unroll
    for (int ni = 0; ni < 2; ++ni)
#pragma unroll
    for (int r = 0; r < 4; ++r) {
        const int row = rowBase + mi*16 + (lane>>4)*4 + r;
        const int col = colBase + ni*16 + (lane&15);
        const int nW = col & 511;
        float v = acc[mi][ni][r] + bias[nW];
        if (seg < 2) v = gelu_exact(v);
        unsigned short h, l;
        split2(v, h, l);
        if (seg == 0)      { Hk_h[(size_t)row*512 + nW] = h; Hk_l[(size_t)row*512 + nW] = l; }
        else if (seg == 1) { Hq_h[(size_t)row*512 + nW] = h; Hq_l[(size_t)row*512 + nW] = l; }
        else {
            const size_t o = (size_t)((row >> 10)*512 + nW) * 1024 + (row & 1023);
            Vt_h[o] = h; Vt_l[o] = l;
        }
    }
}

// ---------------------------------------------------------------------------
// Phase heads: p = tanh(H @ W2 + b2)*pi; CS row = [cos(64) | sin(64)] hi/lo.
// blockIdx.x: bit0 = col half (0/32), bit1 = encoder (0=key,1=query)
// ---------------------------------------------------------------------------
__global__ __launch_bounds__(256) void phase_mfma(
    const unsigned short* __restrict__ Hk_h, const unsigned short* __restrict__ Hk_l,
    const unsigned short* __restrict__ Hq_h, const unsigned short* __restrict__ Hq_l,
    const unsigned short* __restrict__ Wt_h, const unsigned short* __restrict__ Wt_l,
    const float* __restrict__ bk2, const float* __restrict__ bq2,
    unsigned short* __restrict__ CSk_h, unsigned short* __restrict__ CSk_l,
    unsigned short* __restrict__ CSq_h, unsigned short* __restrict__ CSq_l)
{
    const int wid = threadIdx.x >> 6, lane = threadIdx.x & 63;
    const int enc = blockIdx.x >> 1;
    const int colBase = (blockIdx.x & 1) * 32;
    const int tTile = blockIdx.y * 4 + wid;
    const unsigned short* Ah = enc ? Hq_h : Hk_h;
    const unsigned short* Al = enc ? Hq_l : Hk_l;
    const float* b2 = enc ? bq2 : bk2;
    unsigned short* Ch = enc ? CSq_h : CSk_h;
    unsigned short* Cl = enc ? CSq_l : CSk_l;
    f32x4 acc[2][2]; acc_zero(acc);
    wave_gemm32(Ah, Al, 512, tTile*32, Wt_h, Wt_l, 512, 2048 + enc*64 + colBase, 16, acc);
#pragma unroll
    for (int mi = 0; mi < 2; ++mi)
#pragma unroll
    for (int ni = 0; ni < 2; ++ni)
#pragma unroll
    for (int r = 0; r < 4; ++r) {
        const int row = tTile*32 + mi*16 + (lane>>4)*4 + r;
        const int j = colBase + ni*16 + (lane&15);
        float p = acc[mi][ni][r] + b2[j];
        p = tanhf(p) * PI_F;
        float s, c;
        sincosf(p, &s, &c);
        unsigned short h, l;
        split2(c, h, l);
        Ch[(size_t)row*128 + j] = h; Cl[(size_t)row*128 + j] = l;
        split2(s, h, l);
        Ch[(size_t)row*128 + 64 + j] = h; Cl[(size_t)row*128 + 64 + j] = l;
    }
}

// ---------------------------------------------------------------------------
// Scores: A[b,t,s] = CSq[b,t,:].CSk[b,s,:] (K=128), zero for s>t on diagonal.
// ---------------------------------------------------------------------------
__global__ __launch_bounds__(256) void scores_mfma(
    const unsigned short* __restrict__ CSq_h, const unsigned short* __restrict__ CSq_l,
    const unsigned short* __restrict__ CSk_h, const unsigned short* __restrict__ CSk_l,
    unsigned short* __restrict__ Ah_out, unsigned short* __restrict__ Al_out)
{
    const int wid = threadIdx.x >> 6, lane = threadIdx.x & 63;
    const int sT = blockIdx.x;
    const int tTile = blockIdx.y * 4 + wid;
    const int b = blockIdx.z;
    if (sT > tTile) return;
    f32x4 acc[2][2]; acc_zero(acc);
    wave_gemm32(CSq_h, CSq_l, 128, b*1024 + tTile*32,
                CSk_h, CSk_l, 128, b*1024 + sT*32, 4, acc);
#pragma unroll
    for (int mi = 0; mi < 2; ++mi)
#pragma unroll
    for (int ni = 0; ni < 2; ++ni)
#pragma unroll
    for (int r = 0; r < 4; ++r) {
        const int t = tTile*32 + mi*16 + (lane>>4)*4 + r;
        const int s = sT*32 + ni*16 + (lane&15);
        float v = (s <= t) ? acc[mi][ni][r] : 0.f;
        unsigned short h, l;
        split2(v, h, l);
        const size_t o = ((size_t)b*1024 + t) * 1024 + s;
        Ah_out[o] = h; Al_out[o] = l;
    }
}

// ---------------------------------------------------------------------------
// Causal AV: R[b,t,d] = sum_{s<=t} A[b,t,s] * V[b,s,d]  (A upper-tri = 0)
// ---------------------------------------------------------------------------
__global__ __launch_bounds__(256) void av_mfma(
    const unsigned short* __restrict__ Ah, const unsigned short* __restrict__ Al,
    const unsigned short* __restrict__ Vt_h, const unsigned short* __restrict__ Vt_l,
    float* __restrict__ R)
{
    const int wid = threadIdx.x >> 6, lane = threadIdx.x & 63;
    const int dT = blockIdx.x;
    const int tTile = blockIdx.y * 4 + wid;
    const int b = blockIdx.z;
    f32x4 acc[2][2]; acc_zero(acc);
    wave_gemm32(Ah, Al, 1024, b*1024 + tTile*32,
                Vt_h, Vt_l, 1024, b*512 + dT*32, tTile + 1, acc);
#pragma unroll
    for (int mi = 0; mi < 2; ++mi)
#pragma unroll
    for (int ni = 0; ni < 2; ++ni)
#pragma unroll
    for (int r = 0; r < 4; ++r) {
        const int row = b*1024 + tTile*32 + mi*16 + (lane>>4)*4 + r;
        const int d = dT*32 + ni*16 + (lane&15);
        R[(size_t)row*512 + d] = acc[mi][ni][r];
    }
}

// ---------------------------------------------------------------------------
// LN( R / sqrt((t+1)*K) ) * g + b -> Y hi/lo bf16
// ---------------------------------------------------------------------------
__global__ __launch_bounds__(256) void ln_kernel(
    const float* __restrict__ R, const float* __restrict__ g,
    const float* __restrict__ bb,
    unsigned short* __restrict__ Yh, unsigned short* __restrict__ Yl)
{
    const int row = blockIdx.x;
    const int t = row & (L_SEQ - 1);
    const int tid = threadIdx.x;
    const float scale = rsqrtf((float)(t + 1) * 64.0f);
    const float v0 = R[(size_t)row * 512 + tid] * scale;
    const float v1 = R[(size_t)row * 512 + 256 + tid] * scale;
    __shared__ float sbuf[512];
    sbuf[tid]       = v0 + v1;
    sbuf[256 + tid] = v0 * v0 + v1 * v1;
    __syncthreads();
    for (int off = 128; off > 0; off >>= 1) {
        if (tid < off) {
            sbuf[tid]       += sbuf[tid + off];
            sbuf[256 + tid] += sbuf[256 + tid + off];
        }
        __syncthreads();
    }
    const float mu  = sbuf[0] * (1.f / 512.f);
    const float var = sbuf[256] * (1.f / 512.f) - mu * mu;
    const float rr = rsqrtf(var + 1e-5f);
    const float y0 = (v0 - mu) * rr * g[tid]       + bb[tid];
    const float y1 = (v1 - mu) * rr * g[256 + tid] + bb[256 + tid];
    unsigned short h, l;
    split2(y0, h, l);
    Yh[(size_t)row*512 + tid] = h;       Yl[(size_t)row*512 + tid] = l;
    split2(y1, h, l);
    Yh[(size_t)row*512 + 256 + tid] = h; Yl[(size_t)row*512 + 256 + tid] = l;
}

// ---------------------------------------------------------------------------
// out = x + Y @ Wo + bo
// ---------------------------------------------------------------------------
__global__ __launch_bounds__(256) void out_mfma(
    const unsigned short* __restrict__ Yh, const unsigned short* __restrict__ Yl,
    const unsigned short* __restrict__ Wt_h, const unsigned short* __restrict__ Wt_l,
    const float* __restrict__ bo, const float* __restrict__ x,
    float* __restrict__ out)
{
    const int wid = threadIdx.x >> 6, lane = threadIdx.x & 63;
    const int nT = blockIdx.x;
    const int tTile = blockIdx.y * 4 + wid;
    f32x4 acc[2][2]; acc_zero(acc);
    wave_gemm32(Yh, Yl, 512, tTile*32, Wt_h, Wt_l, 512, 1536 + nT*32, 16, acc);
#pragma unroll
    for (int mi = 0; mi < 2; ++mi)
#pragma unroll
    for (int ni = 0; ni < 2; ++ni)
#pragma unroll
    for (int r = 0; r < 4; ++r) {
        const int row = tTile*32 + mi*16 + (lane>>4)*4 + r;
        const int col = nT*32 + ni*16 + (lane&15);
        out[(size_t)row*512 + col] =
            acc[mi][ni][r] + bo[col] + x[(size_t)row*512 + col];
    }
}

// ---------------------------------------------------------------------------
extern "C" void kernel_launch(void* const* d_in, const int* in_sizes, int n_in,
                              void* d_out, int out_size, void* d_ws, size_t ws_size,
                              hipStream_t stream)
{
    const float* x   = (const float*)d_in[0];
    const float* Wk1 = (const float*)d_in[1];
    const float* bk1 = (const float*)d_in[2];
    const float* Wk2 = (const float*)d_in[3];
    const float* bk2 = (const float*)d_in[4];
    const float* Wq1 = (const float*)d_in[5];
    const float* bq1 = (const float*)d_in[6];
    const float* Wq2 = (const float*)d_in[7];
    const float* bq2 = (const float*)d_in[8];
    const float* Wv  = (const float*)d_in[9];
    const float* bv  = (const float*)d_in[10];
    const float* lng = (const float*)d_in[11];
    const float* lnb = (const float*)d_in[12];
    const float* Wo  = (const float*)d_in[13];
    const float* bo  = (const float*)d_in[14];
    float* out = (float*)d_out;

    unsigned short* us = (unsigned short*)d_ws;
    size_t o = 0;
    unsigned short* Wt_h  = us + o; o += (size_t)2176*512;
    unsigned short* Wt_l  = us + o; o += (size_t)2176*512;
    unsigned short* Xh    = us + o; o += (size_t)2048*512;
    unsigned short* Xl    = us + o; o += (size_t)2048*512;
    unsigned short* Hk_h  = us + o; o += (size_t)2048*512;
    unsigned short* Hk_l  = us + o; o += (size_t)2048*512;
    unsigned short* Hq_h  = us + o; o += (size_t)2048*512;
    unsigned short* Hq_l  = us + o; o += (size_t)2048*512;
    unsigned short* Vt_h  = us + o; o += (size_t)2*512*1024;
    unsigned short* Vt_l  = us + o; o += (size_t)2*512*1024;
    unsigned short* CSk_h = us + o; o += (size_t)2048*128;
    unsigned short* CSk_l = us + o; o += (size_t)2048*128;
    unsigned short* CSq_h = us + o; o += (size_t)2048*128;
    unsigned short* CSq_l = us + o; o += (size_t)2048*128;
    unsigned short* Ah    = us + o; o += (size_t)2*1024*1024;
    unsigned short* Al    = us + o; o += (size_t)2*1024*1024;
    float* R = (float*)(us + o);    o += (size_t)2048*512*2;   // fp32
    unsigned short* Yh = Xh;  // alias: X no longer needed after qkv
    unsigned short* Yl = Xl;

    prep_w<<<dim3(8, 34), 256, 0, stream>>>(Wk1, Wq1, Wv, Wo, Wk2, Wq2, Wt_h, Wt_l);
    prep_x<<<dim3(1024), 256, 0, stream>>>(x, Xh, Xl);
    qkv_mfma<<<dim3(48, 16), 256, 0, stream>>>(
        Xh, Xl, Wt_h, Wt_l, bk1, bq1, bv, Hk_h, Hk_l, Hq_h, Hq_l, Vt_h, Vt_l);
    phase_mfma<<<dim3(4, 16), 256, 0, stream>>>(
        Hk_h, Hk_l, Hq_h, Hq_l, Wt_h, Wt_l, bk2, bq2, CSk_h, CSk_l, CSq_h, CSq_l);
    scores_mfma<<<dim3(32, 8, 2), 256, 0, stream>>>(
        CSq_h, CSq_l, CSk_h, CSk_l, Ah, Al);
    av_mfma<<<dim3(16, 8, 2), 256, 0, stream>>>(Ah, Al, Vt_h, Vt_l, R);
    ln_kernel<<<2048, 256, 0, stream>>>(R, lng, lnb, Yh, Yl);
    out_mfma<<<dim3(16, 16), 256, 0, stream>>>(Yh, Yl, Wt_h, Wt_l, bo, x, out);
}

// Round 5
// 180.895 us; speedup vs baseline: 1.6484x; 1.2535x over previous
//
#include <hip/hip_runtime.h>
#include <math.h>

#define L_SEQ 1024
#define M_ROWS 2048
#define PI_F 3.14159265358979323846f

typedef short bf16x8 __attribute__((ext_vector_type(8)));
typedef float f32x4 __attribute__((ext_vector_type(4)));

__device__ __forceinline__ unsigned short bf16_rne(float x) {
    union { float f; unsigned u; } v; v.f = x;
    unsigned r = v.u + 0x7fffu + ((v.u >> 16) & 1u);
    return (unsigned short)(r >> 16);
}
__device__ __forceinline__ float bf16_tof(unsigned short h) {
    union { unsigned u; float f; } v; v.u = ((unsigned)h) << 16;
    return v.f;
}
__device__ __forceinline__ void split2(float x, unsigned short &h, unsigned short &l) {
    h = bf16_rne(x);
    l = bf16_rne(x - bf16_tof(h));
}
__device__ __forceinline__ float gelu_exact(float x) {
    return 0.5f * x * (1.0f + erff(x * 0.70710678118654752f));
}
__device__ __forceinline__ f32x4 mfma16(bf16x8 a, bf16x8 b, f32x4 c) {
    return __builtin_amdgcn_mfma_f32_16x16x32_bf16(a, b, c, 0, 0, 0);
}

// global -> LDS direct copy, 16B per lane. LDS dest must be wave-uniform base;
// HW adds lane*16.
__device__ __forceinline__ void gload_lds16(const unsigned short* g, unsigned short* l) {
    __builtin_amdgcn_global_load_lds(
        (const __attribute__((address_space(1))) void*)g,
        (__attribute__((address_space(3))) void*)l, 16, 0, 0);
}

// ---------------------------------------------------------------------------
// Stage one [R rows x 32 k] bf16 tile into LDS (row = 64B). Source k-chunk is
// pre-swizzled: LDS[r][sl] = G[r][k0 + (sl ^ swz(r))*8], swz(r) = (r>>1)&3.
// Read side uses slot = j ^ swz(r) -> same involution, conflict-free-ish (2-way).
// ---------------------------------------------------------------------------
__device__ __forceinline__ void stage_tile(
    const unsigned short* __restrict__ src, int ld, int rowBase, int k0,
    unsigned short* lds_tile, int R)
{
    const int tid = threadIdx.x;
    for (int i = 0; i < (R >> 6); ++i) {
        const int r = i * 64 + (tid >> 2);
        const int c = (tid & 3) ^ ((r >> 1) & 3);
        const unsigned short* g = src + (size_t)(rowBase + r) * ld + k0 + c * 8;
        unsigned short* l = lds_tile + i * 2048 + (tid & 192) * 8;  // wave-uniform
        gload_lds16(g, l);
    }
}

// ---------------------------------------------------------------------------
// LDS-staged split-bf16 GEMM core. Block = 256 threads = 4 waves (2x2).
// Block tile = (MI*32) x (NI*32); wave tile = (MI*16) x (NI*16).
// A[h,l]: [M][k] row-major, B[h,l]: [N][k] row-major (transposed operand).
// One barrier per K-step: stage(next) issued before compute(cur), drained by
// the vmcnt(0) the compiler emits at the next barrier -> latency hides.
// ---------------------------------------------------------------------------
template<int MI, int NI>
__device__ __forceinline__ void lds_gemm(
    unsigned short* lds,
    const unsigned short* __restrict__ Ah_, const unsigned short* __restrict__ Al_,
    int lda, int aRow,
    const unsigned short* __restrict__ Bh_, const unsigned short* __restrict__ Bl_,
    int ldb, int bRow,
    int k0, int nk, f32x4 (&acc)[MI][NI])
{
    constexpr int SZA = MI * 32 * 32;           // elements per A tile (h or l)
    constexpr int SZB = NI * 32 * 32;
    constexpr int BUF = 2 * SZA + 2 * SZB;      // elements per buffer
    const int tid = threadIdx.x, lane = tid & 63;
    const int wm = (tid >> 7) & 1, wn = (tid >> 6) & 1;

    // prologue: stage K-step 0 into buf0
    stage_tile(Ah_, lda, aRow, k0, lds,                 MI * 32);
    stage_tile(Al_, lda, aRow, k0, lds + SZA,           MI * 32);
    stage_tile(Bh_, ldb, bRow, k0, lds + 2 * SZA,       NI * 32);
    stage_tile(Bl_, ldb, bRow, k0, lds + 2 * SZA + SZB, NI * 32);

    for (int ks = 0; ks < nk; ++ks) {
        const int cur = (ks & 1) * BUF;
        const int nxt = ((ks & 1) ^ 1) * BUF;
        __syncthreads();   // drains prev stage (vmcnt0); frees nxt buffer
        if (ks + 1 < nk) {
            const int kk = k0 + (ks + 1) * 32;
            stage_tile(Ah_, lda, aRow, kk, lds + nxt,                 MI * 32);
            stage_tile(Al_, lda, aRow, kk, lds + nxt + SZA,           MI * 32);
            stage_tile(Bh_, ldb, bRow, kk, lds + nxt + 2 * SZA,       NI * 32);
            stage_tile(Bl_, ldb, bRow, kk, lds + nxt + 2 * SZA + SZB, NI * 32);
        }
        const int lr = lane & 15, j = lane >> 4;
        bf16x8 ah[MI], al[MI], bh[NI], bl[NI];
#pragma unroll
        for (int mi = 0; mi < MI; ++mi) {
            const int r = wm * (MI * 16) + mi * 16 + lr;
            const int off = cur + r * 32 + ((j ^ ((r >> 1) & 3)) << 3);
            ah[mi] = *(const bf16x8*)(lds + off);
            al[mi] = *(const bf16x8*)(lds + off + SZA);
        }
#pragma unroll
        for (int ni = 0; ni < NI; ++ni) {
            const int r = wn * (NI * 16) + ni * 16 + lr;
            const int off = cur + 2 * SZA + r * 32 + ((j ^ ((r >> 1) & 3)) << 3);
            bh[ni] = *(const bf16x8*)(lds + off);
            bl[ni] = *(const bf16x8*)(lds + off + SZB);
        }
#pragma unroll
        for (int mi = 0; mi < MI; ++mi)
#pragma unroll
            for (int ni = 0; ni < NI; ++ni) {
                acc[mi][ni] = mfma16(ah[mi], bh[ni], acc[mi][ni]);
                acc[mi][ni] = mfma16(ah[mi], bl[ni], acc[mi][ni]);
                acc[mi][ni] = mfma16(al[mi], bh[ni], acc[mi][ni]);
            }
    }
}

// ---------------------------------------------------------------------------
// Direct-from-L2 32x32 core (kept for the small phase GEMM only).
// ---------------------------------------------------------------------------
__device__ __forceinline__ void wave_gemm32(
    const unsigned short* __restrict__ Ah, const unsigned short* __restrict__ Al,
    int lda, int aRow,
    const unsigned short* __restrict__ Bh, const unsigned short* __restrict__ Bl,
    int ldb, int bRow,
    int nk, f32x4 (&acc)[2][2])
{
    const int lane = threadIdx.x & 63;
    const int lr = lane & 15;
    const int lk = (lane >> 4) << 3;
    const size_t a0 = (size_t)(aRow + lr) * lda + lk;
    const size_t a1 = a0 + (size_t)16 * lda;
    const size_t b0 = (size_t)(bRow + lr) * ldb + lk;
    const size_t b1 = b0 + (size_t)16 * ldb;
#define LDF(P, O, K) (*reinterpret_cast<const bf16x8*>((P) + (O) + (size_t)(K)))
#pragma unroll 4
    for (int ks = 0; ks < nk; ++ks) {
        const int kk = ks * 32;
        bf16x8 a0h = LDF(Ah,a0,kk), a0l = LDF(Al,a0,kk);
        bf16x8 a1h = LDF(Ah,a1,kk), a1l = LDF(Al,a1,kk);
        bf16x8 b0h = LDF(Bh,b0,kk), b0l = LDF(Bl,b0,kk);
        bf16x8 b1h = LDF(Bh,b1,kk), b1l = LDF(Bl,b1,kk);
        acc[0][0] = mfma16(a0h, b0h, acc[0][0]);
        acc[0][0] = mfma16(a0h, b0l, acc[0][0]);
        acc[0][0] = mfma16(a0l, b0h, acc[0][0]);
        acc[0][1] = mfma16(a0h, b1h, acc[0][1]);
        acc[0][1] = mfma16(a0h, b1l, acc[0][1]);
        acc[0][1] = mfma16(a0l, b1h, acc[0][1]);
        acc[1][0] = mfma16(a1h, b0h, acc[1][0]);
        acc[1][0] = mfma16(a1h, b0l, acc[1][0]);
        acc[1][0] = mfma16(a1l, b0h, acc[1][0]);
        acc[1][1] = mfma16(a1h, b1h, acc[1][1]);
        acc[1][1] = mfma16(a1h, b1l, acc[1][1]);
        acc[1][1] = mfma16(a1l, b1h, acc[1][1]);
    }
#undef LDF
}

// ---------------------------------------------------------------------------
// prep_w: transpose + hi/lo split all weights into Wt[row=n][k] bf16.
// rows: [0,512)=Wk1^T, [512,1024)=Wq1^T, [1024,1536)=Wv^T,
//       [1536,2048)=Wo^T, [2048,2112)=Wk2^T, [2112,2176)=Wq2^T
// ---------------------------------------------------------------------------
__global__ __launch_bounds__(256) void prep_w(
    const float* __restrict__ Wk1, const float* __restrict__ Wq1,
    const float* __restrict__ Wv,  const float* __restrict__ Wo,
    const float* __restrict__ Wk2, const float* __restrict__ Wq2,
    unsigned short* __restrict__ Wt_h, unsigned short* __restrict__ Wt_l)
{
    const int ty = blockIdx.y;   // 0..33
    const int kT = blockIdx.x;   // 0..7
    const float* src; int srcN; int dstRowBase; int nBase;
    if (ty < 8)       { src = Wk1; srcN = 512; dstRowBase = 0;    nBase = ty * 64; }
    else if (ty < 16) { src = Wq1; srcN = 512; dstRowBase = 512;  nBase = (ty-8)*64; }
    else if (ty < 24) { src = Wv;  srcN = 512; dstRowBase = 1024; nBase = (ty-16)*64; }
    else if (ty < 32) { src = Wo;  srcN = 512; dstRowBase = 1536; nBase = (ty-24)*64; }
    else if (ty == 32){ src = Wk2; srcN = 64;  dstRowBase = 2048; nBase = 0; }
    else              { src = Wq2; srcN = 64;  dstRowBase = 2112; nBase = 0; }
    __shared__ float T[64][65];
    const int tid = threadIdx.x;
    const int k0 = kT * 64;
    {
        const int r = tid >> 2;
        const int c0 = (tid & 3) * 16;
#pragma unroll
        for (int i = 0; i < 4; ++i) {
            float4 v = *reinterpret_cast<const float4*>(
                src + (size_t)(k0 + r) * srcN + nBase + c0 + i*4);
            T[r][c0+i*4+0] = v.x; T[r][c0+i*4+1] = v.y;
            T[r][c0+i*4+2] = v.z; T[r][c0+i*4+3] = v.w;
        }
    }
    __syncthreads();
    {
        const int n = tid >> 2;
        const int kk0 = (tid & 3) * 16;
        const size_t base = (size_t)(dstRowBase + nBase + n) * 512 + k0 + kk0;
#pragma unroll
        for (int i = 0; i < 16; ++i) {
            unsigned short h, l;
            split2(T[kk0 + i][n], h, l);
            Wt_h[base + i] = h; Wt_l[base + i] = l;
        }
    }
}

// x [2048][512] f32 -> Xh, Xl bf16 (no transpose)
__global__ __launch_bounds__(256) void prep_x(
    const float* __restrict__ x,
    unsigned short* __restrict__ Xh, unsigned short* __restrict__ Xl)
{
    const size_t i = (size_t)blockIdx.x * 256 + threadIdx.x;  // float4 index
    float4 v = reinterpret_cast<const float4*>(x)[i];
    unsigned short h0,h1,h2,h3, l0,l1,l2,l3;
    split2(v.x, h0, l0); split2(v.y, h1, l1);
    split2(v.z, h2, l2); split2(v.w, h3, l3);
    unsigned long long hp = (unsigned long long)h0 | ((unsigned long long)h1<<16)
                          | ((unsigned long long)h2<<32) | ((unsigned long long)h3<<48);
    unsigned long long lp = (unsigned long long)l0 | ((unsigned long long)l1<<16)
                          | ((unsigned long long)l2<<32) | ((unsigned long long)l3<<48);
    reinterpret_cast<unsigned long long*>(Xh)[i] = hp;
    reinterpret_cast<unsigned long long*>(Xl)[i] = lp;
}

// ---------------------------------------------------------------------------
// Fused QKV: N-cols [0,512)=gelu->Hk, [512,1024)=gelu->Hq, [1024,1536)->Vt^T
// ---------------------------------------------------------------------------
__global__ __launch_bounds__(256) void qkv_mfma(
    const unsigned short* __restrict__ Xh, const unsigned short* __restrict__ Xl,
    const unsigned short* __restrict__ Wt_h, const unsigned short* __restrict__ Wt_l,
    const float* __restrict__ bk1, const float* __restrict__ bq1, const float* __restrict__ bv,
    unsigned short* __restrict__ Hk_h, unsigned short* __restrict__ Hk_l,
    unsigned short* __restrict__ Hq_h, unsigned short* __restrict__ Hq_l,
    unsigned short* __restrict__ Vt_h, unsigned short* __restrict__ Vt_l)
{
    __shared__ unsigned short lds[32768];  // 64KB
    const int lane = threadIdx.x & 63;
    const int wm = (threadIdx.x >> 7) & 1, wn = (threadIdx.x >> 6) & 1;
    const int mBase = blockIdx.y * 128, nBase = blockIdx.x * 128;
    f32x4 acc[4][4];
#pragma unroll
    for (int i = 0; i < 4; ++i)
#pragma unroll
        for (int jj = 0; jj < 4; ++jj) acc[i][jj] = (f32x4){0.f,0.f,0.f,0.f};
    lds_gemm<4,4>(lds, Xh, Xl, 512, mBase, Wt_h, Wt_l, 512, nBase, 0, 16, acc);

    const int seg = nBase >> 9;
    const float* bias = (seg == 0) ? bk1 : (seg == 1) ? bq1 : bv;
#pragma unroll
    for (int mi = 0; mi < 4; ++mi)
#pragma unroll
    for (int ni = 0; ni < 4; ++ni)
#pragma unroll
    for (int r = 0; r < 4; ++r) {
        const int row = mBase + wm*64 + mi*16 + (lane>>4)*4 + r;
        const int col = nBase + wn*64 + ni*16 + (lane&15);
        const int nW = col & 511;
        float v = acc[mi][ni][r] + bias[nW];
        if (seg < 2) v = gelu_exact(v);
        unsigned short h, l;
        split2(v, h, l);
        if (seg == 0)      { Hk_h[(size_t)row*512 + nW] = h; Hk_l[(size_t)row*512 + nW] = l; }
        else if (seg == 1) { Hq_h[(size_t)row*512 + nW] = h; Hq_l[(size_t)row*512 + nW] = l; }
        else {
            const size_t o = (size_t)((row >> 10)*512 + nW) * 1024 + (row & 1023);
            Vt_h[o] = h; Vt_l[o] = l;
        }
    }
}

// ---------------------------------------------------------------------------
// Phase heads (small GEMM, direct-L2): p = tanh(H@W2+b2)*pi -> [cos|sin] hi/lo
// ---------------------------------------------------------------------------
__global__ __launch_bounds__(256) void phase_mfma(
    const unsigned short* __restrict__ Hk_h, const unsigned short* __restrict__ Hk_l,
    const unsigned short* __restrict__ Hq_h, const unsigned short* __restrict__ Hq_l,
    const unsigned short* __restrict__ Wt_h, const unsigned short* __restrict__ Wt_l,
    const float* __restrict__ bk2, const float* __restrict__ bq2,
    unsigned short* __restrict__ CSk_h, unsigned short* __restrict__ CSk_l,
    unsigned short* __restrict__ CSq_h, unsigned short* __restrict__ CSq_l)
{
    const int wid = threadIdx.x >> 6, lane = threadIdx.x & 63;
    const int enc = blockIdx.x >> 1;
    const int colBase = (blockIdx.x & 1) * 32;
    const int tTile = blockIdx.y * 4 + wid;
    const unsigned short* Ah = enc ? Hq_h : Hk_h;
    const unsigned short* Al = enc ? Hq_l : Hk_l;
    const float* b2 = enc ? bq2 : bk2;
    unsigned short* Ch = enc ? CSq_h : CSk_h;
    unsigned short* Cl = enc ? CSq_l : CSk_l;
    f32x4 acc[2][2];
#pragma unroll
    for (int i = 0; i < 2; ++i)
#pragma unroll
        for (int jj = 0; jj < 2; ++jj) acc[i][jj] = (f32x4){0.f,0.f,0.f,0.f};
    wave_gemm32(Ah, Al, 512, tTile*32, Wt_h, Wt_l, 512, 2048 + enc*64 + colBase, 16, acc);
#pragma unroll
    for (int mi = 0; mi < 2; ++mi)
#pragma unroll
    for (int ni = 0; ni < 2; ++ni)
#pragma unroll
    for (int r = 0; r < 4; ++r) {
        const int row = tTile*32 + mi*16 + (lane>>4)*4 + r;
        const int j = colBase + ni*16 + (lane&15);
        float p = acc[mi][ni][r] + b2[j];
        p = tanhf(p) * PI_F;
        float s, c;
        sincosf(p, &s, &c);
        unsigned short h, l;
        split2(c, h, l);
        Ch[(size_t)row*128 + j] = h; Cl[(size_t)row*128 + j] = l;
        split2(s, h, l);
        Ch[(size_t)row*128 + 64 + j] = h; Cl[(size_t)row*128 + 64 + j] = l;
    }
}

// ---------------------------------------------------------------------------
// Scores: A[b,t,s] = CSq[b,t,:].CSk[b,s,:] (K=128); upper-tri of diag zeroed.
// 128x128 tiles, lower-triangular grid.
// ---------------------------------------------------------------------------
__global__ __launch_bounds__(256) void scores_mfma(
    const unsigned short* __restrict__ CSq_h, const unsigned short* __restrict__ CSq_l,
    const unsigned short* __restrict__ CSk_h, const unsigned short* __restrict__ CSk_l,
    unsigned short* __restrict__ Ah_out, unsigned short* __restrict__ Al_out)
{
    const int sT = blockIdx.x, tT = blockIdx.y, b = blockIdx.z;
    if (sT > tT) return;
    __shared__ unsigned short lds[32768];
    const int lane = threadIdx.x & 63;
    const int wm = (threadIdx.x >> 7) & 1, wn = (threadIdx.x >> 6) & 1;
    f32x4 acc[4][4];
#pragma unroll
    for (int i = 0; i < 4; ++i)
#pragma unroll
        for (int jj = 0; jj < 4; ++jj) acc[i][jj] = (f32x4){0.f,0.f,0.f,0.f};
    lds_gemm<4,4>(lds, CSq_h, CSq_l, 128, b*1024 + tT*128,
                  CSk_h, CSk_l, 128, b*1024 + sT*128, 0, 4, acc);
#pragma unroll
    for (int mi = 0; mi < 4; ++mi)
#pragma unroll
    for (int ni = 0; ni < 4; ++ni)
#pragma unroll
    for (int r = 0; r < 4; ++r) {
        const int t = tT*128 + wm*64 + mi*16 + (lane>>4)*4 + r;
        const int s = sT*128 + wn*64 + ni*16 + (lane&15);
        float v = (s <= t) ? acc[mi][ni][r] : 0.f;
        unsigned short h, l;
        split2(v, h, l);
        const size_t o = ((size_t)b*1024 + t) * 1024 + s;
        Ah_out[o] = h; Al_out[o] = l;
    }
}

// ---------------------------------------------------------------------------
// Causal AV with s-chunking: chunk c covers s in [c*256, c*256+256).
// Rp[c][b,t,d] = sum_{s in chunk, s <= tTile range} A[b,t,s]*V[b,s,d].
// Upper-tri zeros in A make the diagonal chunk exact.
// ---------------------------------------------------------------------------
__global__ __launch_bounds__(256) void av_mfma(
    const unsigned short* __restrict__ Ah, const unsigned short* __restrict__ Al,
    const unsigned short* __restrict__ Vt_h, const unsigned short* __restrict__ Vt_l,
    float* __restrict__ Rp)
{
    const int dT = blockIdx.x;           // 0..3 (128 cols of D)
    const int tT = blockIdx.y;           // 0..7 (128 rows of t)
    const int b = blockIdx.z >> 2, c = blockIdx.z & 3;
    if (c > (tT >> 1)) return;
    __shared__ unsigned short lds[32768];
    const int lane = threadIdx.x & 63;
    const int wm = (threadIdx.x >> 7) & 1, wn = (threadIdx.x >> 6) & 1;
    const int kLen = min(256, tT*128 + 128 - c*256);
    const int nk = kLen >> 5;            // 4 or 8
    f32x4 acc[4][4];
#pragma unroll
    for (int i = 0; i < 4; ++i)
#pragma unroll
        for (int jj = 0; jj < 4; ++jj) acc[i][jj] = (f32x4){0.f,0.f,0.f,0.f};
    lds_gemm<4,4>(lds, Ah, Al, 1024, b*1024 + tT*128,
                  Vt_h, Vt_l, 1024, b*512 + dT*128, c*256, nk, acc);
    float* Rb = Rp + (size_t)c * (M_ROWS * 512);
#pragma unroll
    for (int mi = 0; mi < 4; ++mi)
#pragma unroll
    for (int ni = 0; ni < 4; ++ni)
#pragma unroll
    for (int r = 0; r < 4; ++r) {
        const int row = b*1024 + tT*128 + wm*64 + mi*16 + (lane>>4)*4 + r;
        const int d = dT*128 + wn*64 + ni*16 + (lane&15);
        Rb[(size_t)row*512 + d] = acc[mi][ni][r];
    }
}

// ---------------------------------------------------------------------------
// LN( (sum_c Rp[c]) / sqrt((t+1)*K) ) * g + b -> Y hi/lo bf16
// ---------------------------------------------------------------------------
__global__ __launch_bounds__(256) void ln_kernel(
    const float* __restrict__ Rp, const float* __restrict__ g,
    const float* __restrict__ bb,
    unsigned short* __restrict__ Yh, unsigned short* __restrict__ Yl)
{
    const int row = blockIdx.x;
    const int t = row & (L_SEQ - 1);
    const int nc = (t >> 8) + 1;
    const int tid = threadIdx.x;
    const float scale = rsqrtf((float)(t + 1) * 64.0f);
    float v0 = 0.f, v1 = 0.f;
    for (int c = 0; c < nc; ++c) {
        const float* Rr = Rp + (size_t)c * (M_ROWS * 512) + (size_t)row * 512;
        v0 += Rr[tid];
        v1 += Rr[256 + tid];
    }
    v0 *= scale; v1 *= scale;
    __shared__ float sbuf[512];
    sbuf[tid]       = v0 + v1;
    sbuf[256 + tid] = v0 * v0 + v1 * v1;
    __syncthreads();
    for (int off = 128; off > 0; off >>= 1) {
        if (tid < off) {
            sbuf[tid]       += sbuf[tid + off];
            sbuf[256 + tid] += sbuf[256 + tid + off];
        }
        __syncthreads();
    }
    const float mu  = sbuf[0] * (1.f / 512.f);
    const float var = sbuf[256] * (1.f / 512.f) - mu * mu;
    const float rr = rsqrtf(var + 1e-5f);
    const float y0 = (v0 - mu) * rr * g[tid]       + bb[tid];
    const float y1 = (v1 - mu) * rr * g[256 + tid] + bb[256 + tid];
    unsigned short h, l;
    split2(y0, h, l);
    Yh[(size_t)row*512 + tid] = h;       Yl[(size_t)row*512 + tid] = l;
    split2(y1, h, l);
    Yh[(size_t)row*512 + 256 + tid] = h; Yl[(size_t)row*512 + 256 + tid] = l;
}

// ---------------------------------------------------------------------------
// out = x + Y @ Wo + bo.  128x64 tiles -> 128 blocks.
// ---------------------------------------------------------------------------
__global__ __launch_bounds__(256) void out_mfma(
    const unsigned short* __restrict__ Yh, const unsigned short* __restrict__ Yl,
    const unsigned short* __restrict__ Wt_h, const unsigned short* __restrict__ Wt_l,
    const float* __restrict__ bo, const float* __restrict__ x,
    float* __restrict__ out)
{
    __shared__ unsigned short lds[24576];  // 48KB
    const int lane = threadIdx.x & 63;
    const int wm = (threadIdx.x >> 7) & 1, wn = (threadIdx.x >> 6) & 1;
    const int nT = blockIdx.x;             // 0..7, 64 cols each
    const int mBase = blockIdx.y * 128;
    f32x4 acc[4][2];
#pragma unroll
    for (int i = 0; i < 4; ++i)
#pragma unroll
        for (int jj = 0; jj < 2; ++jj) acc[i][jj] = (f32x4){0.f,0.f,0.f,0.f};
    lds_gemm<4,2>(lds, Yh, Yl, 512, mBase, Wt_h, Wt_l, 512, 1536 + nT*64, 0, 16, acc);
#pragma unroll
    for (int mi = 0; mi < 4; ++mi)
#pragma unroll
    for (int ni = 0; ni < 2; ++ni)
#pragma unroll
    for (int r = 0; r < 4; ++r) {
        const int row = mBase + wm*64 + mi*16 + (lane>>4)*4 + r;
        const int col = nT*64 + wn*32 + ni*16 + (lane&15);
        out[(size_t)row*512 + col] =
            acc[mi][ni][r] + bo[col] + x[(size_t)row*512 + col];
    }
}

// ---------------------------------------------------------------------------
extern "C" void kernel_launch(void* const* d_in, const int* in_sizes, int n_in,
                              void* d_out, int out_size, void* d_ws, size_t ws_size,
                              hipStream_t stream)
{
    const float* x   = (const float*)d_in[0];
    const float* Wk1 = (const float*)d_in[1];
    const float* bk1 = (const float*)d_in[2];
    const float* Wk2 = (const float*)d_in[3];
    const float* bk2 = (const float*)d_in[4];
    const float* Wq1 = (const float*)d_in[5];
    const float* bq1 = (const float*)d_in[6];
    const float* Wq2 = (const float*)d_in[7];
    const float* bq2 = (const float*)d_in[8];
    const float* Wv  = (const float*)d_in[9];
    const float* bv  = (const float*)d_in[10];
    const float* lng = (const float*)d_in[11];
    const float* lnb = (const float*)d_in[12];
    const float* Wo  = (const float*)d_in[13];
    const float* bo  = (const float*)d_in[14];
    float* out = (float*)d_out;

    unsigned short* us = (unsigned short*)d_ws;
    size_t o = 0;
    unsigned short* Wt_h  = us + o; o += (size_t)2176*512;
    unsigned short* Wt_l  = us + o; o += (size_t)2176*512;
    unsigned short* Xh    = us + o; o += (size_t)2048*512;
    unsigned short* Xl    = us + o; o += (size_t)2048*512;
    unsigned short* Hk_h  = us + o; o += (size_t)2048*512;
    unsigned short* Hk_l  = us + o; o += (size_t)2048*512;
    unsigned short* Hq_h  = us + o; o += (size_t)2048*512;
    unsigned short* Hq_l  = us + o; o += (size_t)2048*512;
    unsigned short* Vt_h  = us + o; o += (size_t)2*512*1024;
    unsigned short* Vt_l  = us + o; o += (size_t)2*512*1024;
    unsigned short* CSk_h = us + o; o += (size_t)2048*128;
    unsigned short* CSk_l = us + o; o += (size_t)2048*128;
    unsigned short* CSq_h = us + o; o += (size_t)2048*128;
    unsigned short* CSq_l = us + o; o += (size_t)2048*128;
    unsigned short* Ah    = us + o; o += (size_t)2*1024*1024;
    unsigned short* Al    = us + o; o += (size_t)2*1024*1024;
    float* Rp = (float*)(us + o);   o += (size_t)4 * 2048*512 * 2;  // 4 chunks f32
    unsigned short* Yh = Xh;  // alias: X no longer needed after qkv
    unsigned short* Yl = Xl;

    prep_w<<<dim3(8, 34), 256, 0, stream>>>(Wk1, Wq1, Wv, Wo, Wk2, Wq2, Wt_h, Wt_l);
    prep_x<<<dim3(1024), 256, 0, stream>>>(x, Xh, Xl);
    qkv_mfma<<<dim3(12, 16), 256, 0, stream>>>(
        Xh, Xl, Wt_h, Wt_l, bk1, bq1, bv, Hk_h, Hk_l, Hq_h, Hq_l, Vt_h, Vt_l);
    phase_mfma<<<dim3(4, 16), 256, 0, stream>>>(
        Hk_h, Hk_l, Hq_h, Hq_l, Wt_h, Wt_l, bk2, bq2, CSk_h, CSk_l, CSq_h, CSq_l);
    scores_mfma<<<dim3(8, 8, 2), 256, 0, stream>>>(
        CSq_h, CSq_l, CSk_h, CSk_l, Ah, Al);
    av_mfma<<<dim3(4, 8, 8), 256, 0, stream>>>(Ah, Al, Vt_h, Vt_l, Rp);
    ln_kernel<<<2048, 256, 0, stream>>>(Rp, lng, lnb, Yh, Yl);
    out_mfma<<<dim3(8, 16), 256, 0, stream>>>(Yh, Yl, Wt_h, Wt_l, bo, x, out);
}